// Round 6
// baseline (539.920 us; speedup 1.0000x reference)
//
#include <hip/hip_runtime.h>
#include <hip/hip_bf16.h>

// HeteroRGCN, minimal-random-line-op design + MLP-optimized gather:
//   p_c = lrelu(mask(mean_t2c(x) @ W1[1] + b1[1])) @ (W2[0]@W_out) + b2[0]@W_out
//   p_d = same with W1[3], W2[2]
//   out[t] = b_out + mean_c2t(p_c) + mean_d2t(p_d)
// Layer-1: ELL gather (wave-per-node, 8-deep load chunks).
// Layer-2: ONE packed uint64 fixed-point atomicAdd per edge.

#define NT 500000
#define NC 200000
#define ND 100000
#define NE 1000000
#define H  64
#define CAP_T2C 32   // dst NC, lambda=5  (Poisson tail ~1e-15)
#define CAP_T2D 48   // dst ND, lambda=10 (Poisson tail ~1e-19)
#define NBLK_C (NC / 64)          // 3125
#define NBLK_D ((ND + 63) / 64)   // 1563

#define PACK_SCALE 65536.0f
#define PACK_BIAS  262144   // 4 * 65536
#define FIELD_MASK 0x3FFFFFFULL

// ---- build ELL for t2c/t2d (ILP=4) ----
__global__ void build_ell(const int* __restrict__ st2c, const int* __restrict__ dt2c,
                          const int* __restrict__ st2d, const int* __restrict__ dt2d,
                          int* __restrict__ cnt_t2c, int* __restrict__ cols_t2c,
                          int* __restrict__ cnt_t2d, int* __restrict__ cols_t2d) {
    const int Q = NE / 4;  // 250000 threads per relation
    int i = blockIdx.x * blockDim.x + threadIdx.x;
    if (i >= 2 * Q) return;
    int sec = i / Q;
    int r = i - sec * Q;
    const int* sp = (sec == 0) ? st2c : st2d;
    const int* dp = (sec == 0) ? dt2c : dt2d;
    int* cnt = (sec == 0) ? cnt_t2c : cnt_t2d;
    int* cols = (sec == 0) ? cols_t2c : cols_t2d;
    int cap = (sec == 0) ? CAP_T2C : CAP_T2D;
    int4 s4 = ((const int4*)sp)[r];
    int4 d4 = ((const int4*)dp)[r];
    int p0 = atomicAdd(&cnt[d4.x], 1);
    int p1 = atomicAdd(&cnt[d4.y], 1);
    int p2 = atomicAdd(&cnt[d4.z], 1);
    int p3 = atomicAdd(&cnt[d4.w], 1);
    if (p0 < cap) cols[(size_t)d4.x * cap + p0] = s4.x;
    if (p1 < cap) cols[(size_t)d4.y * cap + p1] = s4.y;
    if (p2 < cap) cols[(size_t)d4.z * cap + p2] = s4.z;
    if (p3 < cap) cols[(size_t)d4.w * cap + p3] = s4.w;
}

// ---- fold W2[rel] @ W_out -> Wc (2 x 64 x 2), b2[rel] @ W_out -> bc (2 x 2) ----
__global__ void prep_fold(const float* __restrict__ W2, const float* __restrict__ b2,
                          const float* __restrict__ Wout,
                          float* __restrict__ Wc, float* __restrict__ bc) {
    int t = threadIdx.x;
    int rel = t >> 7;          // 0 -> W2[0], 1 -> W2[2]
    int rem = t & 127;
    int k = rem >> 1, o = rem & 1;
    const float* W2r = W2 + (rel ? 2 : 0) * H * H;
    float s = 0.0f;
    for (int j = 0; j < H; ++j) s += W2r[k * H + j] * Wout[j * 2 + o];
    Wc[rel * 128 + k * 2 + o] = s;
    if (rem < 4) {
        int r2 = rem >> 1, o2 = rem & 1;
        const float* b2r = b2 + (r2 ? 2 : 0) * H;
        float sb = 0.0f;
        for (int j = 0; j < H; ++j) sb += b2r[j] * Wout[j * 2 + o2];
        bc[r2 * 2 + o2] = sb;
    }
}

// ---- fused gather-mean + transform + lrelu + mask + fold, both relations ----
// 1024 threads = 16 waves; 64 nodes/block; wave-per-node gather (4 serial each).
__global__ __launch_bounds__(1024)
void gather_xform(const float* __restrict__ X,
                  const int* __restrict__ cnt_c, const int* __restrict__ cols_c,
                  const int* __restrict__ cnt_d, const int* __restrict__ cols_d,
                  const float* __restrict__ W1, const float* __restrict__ b1,
                  const float* __restrict__ Wc, const float* __restrict__ bc,
                  float* __restrict__ Pc, float* __restrict__ Pd) {
    __shared__ float Xs[64][65];   // [node][k], stride 65 -> conflict-free both phases
    __shared__ float msk[64];
    int t = threadIdx.x;
    int lane = t & 63;
    int w = t >> 6;

    int bn, nNodes, cap;
    const int* cnt; const int* cols;
    const float* W1r; const float* b1r; const float* Wcr; const float* bcr;
    float* P;
    if (blockIdx.x < NBLK_C) {
        bn = blockIdx.x * 64; nNodes = NC; cap = CAP_T2C;
        cnt = cnt_c; cols = cols_c;
        W1r = W1 + 1 * H * H; b1r = b1 + 1 * H; Wcr = Wc; bcr = bc; P = Pc;
    } else {
        bn = (blockIdx.x - NBLK_C) * 64; nNodes = ND; cap = CAP_T2D;
        cnt = cnt_d; cols = cols_d;
        W1r = W1 + 3 * H * H; b1r = b1 + 3 * H; Wcr = Wc + 128; bcr = bc + 2; P = Pd;
    }

    // ---- phase A: wave-per-node gather-mean (4 nodes per wave) ----
    for (int r = 0; r < 4; ++r) {
        int nl = w * 4 + r;
        int gn = bn + nl;
        int c = 0;
        float acc = 0.0f;
        if (gn < nNodes) {
            c = cnt[gn];
            int m = c < cap ? c : cap;
            int colv = (lane < m) ? cols[(size_t)gn * cap + lane] : 0;
            for (int base = 0; base < m; base += 8) {
                int take = m - base;
                float a0 = 0.f, a1 = 0.f, a2 = 0.f, a3 = 0.f;
                float a4 = 0.f, a5 = 0.f, a6 = 0.f, a7 = 0.f;
                a0 = X[(size_t)__shfl(colv, base + 0) * H + lane];
                if (take > 1) a1 = X[(size_t)__shfl(colv, base + 1) * H + lane];
                if (take > 2) a2 = X[(size_t)__shfl(colv, base + 2) * H + lane];
                if (take > 3) a3 = X[(size_t)__shfl(colv, base + 3) * H + lane];
                if (take > 4) a4 = X[(size_t)__shfl(colv, base + 4) * H + lane];
                if (take > 5) a5 = X[(size_t)__shfl(colv, base + 5) * H + lane];
                if (take > 6) a6 = X[(size_t)__shfl(colv, base + 6) * H + lane];
                if (take > 7) a7 = X[(size_t)__shfl(colv, base + 7) * H + lane];
                acc += ((a0 + a1) + (a2 + a3)) + ((a4 + a5) + (a6 + a7));
            }
            if (c > 0) acc *= 1.0f / (float)c;
        }
        Xs[nl][lane] = acc;
        if (lane == 0) msk[nl] = (c > 0) ? 1.0f : 0.0f;
    }
    __syncthreads();

    // ---- phase B: thread = (node t>>4, cols (t&15)*4 .. +3) ----
    int nl = t >> 4;
    int gn = bn + nl;
    int c0 = (t & 15) * 4;
    float4 b4 = *(const float4*)(b1r + c0);
    float h0 = b4.x, h1 = b4.y, h2 = b4.z, h3 = b4.w;
#pragma unroll
    for (int k = 0; k < H; ++k) {
        float xv = Xs[nl][k];                              // LDS broadcast
        float4 wv = *(const float4*)(W1r + k * H + c0);    // global, L1-hot
        h0 = fmaf(xv, wv.x, h0); h1 = fmaf(xv, wv.y, h1);
        h2 = fmaf(xv, wv.z, h2); h3 = fmaf(xv, wv.w, h3);
    }
    float m = msk[nl];
    h0 = (h0 > 0.f ? h0 : 0.01f * h0) * m;
    h1 = (h1 > 0.f ? h1 : 0.01f * h1) * m;
    h2 = (h2 > 0.f ? h2 : 0.01f * h2) * m;
    h3 = (h3 > 0.f ? h3 : 0.01f * h3) * m;
    float4 wca = *(const float4*)(Wcr + c0 * 2);       // cols c0,c0+1 (o=0,1 pairs)
    float4 wcb = *(const float4*)(Wcr + c0 * 2 + 4);   // cols c0+2,c0+3
    float p0 = h0 * wca.x + h1 * wca.z + h2 * wcb.x + h3 * wcb.z;
    float p1 = h0 * wca.y + h1 * wca.w + h2 * wcb.y + h3 * wcb.w;
#pragma unroll
    for (int off = 1; off < 16; off <<= 1) {
        p0 += __shfl_xor(p0, off);
        p1 += __shfl_xor(p1, off);
    }
    if ((t & 15) == 0 && gn < nNodes) {
        P[2 * (size_t)gn + 0] = p0 + bcr[0];
        P[2 * (size_t)gn + 1] = p1 + bcr[1];
    }
}

// ---- pack p into fixed-point uint64 with embedded degree count ----
__device__ __forceinline__ unsigned long long pack_p(const float* __restrict__ P, int s) {
    float2 pv = *(const float2*)(P + 2 * (size_t)s);
    float a = fminf(fmaxf(pv.x, -3.99f), 3.99f);
    float b = fminf(fmaxf(pv.y, -3.99f), 3.99f);
    unsigned int ia = (unsigned int)(__float2int_rn(a * PACK_SCALE) + PACK_BIAS);
    unsigned int ib = (unsigned int)(__float2int_rn(b * PACK_SCALE) + PACK_BIAS);
    return (1ULL << 52) | ((unsigned long long)ia << 26) | (unsigned long long)ib;
}

// ---- layer-2: one uint64 atomic per edge (fire-and-forget), ILP=4 ----
__global__ void scatter_pack(const float* __restrict__ Pc, const float* __restrict__ Pd,
                             const int* __restrict__ sc2t, const int* __restrict__ dc2t,
                             const int* __restrict__ sd2t, const int* __restrict__ dd2t,
                             unsigned long long* __restrict__ acc_c,
                             unsigned long long* __restrict__ acc_d) {
    const int Q = NE / 4;
    int i = blockIdx.x * blockDim.x + threadIdx.x;
    if (i >= 2 * Q) return;
    int rel = i / Q;
    int r = i - rel * Q;
    const int* sp = rel ? sd2t : sc2t;
    const int* dp = rel ? dd2t : dc2t;
    const float* P = rel ? Pd : Pc;
    unsigned long long* acc = rel ? acc_d : acc_c;
    int4 s4 = ((const int4*)sp)[r];
    int4 d4 = ((const int4*)dp)[r];
    unsigned long long v0 = pack_p(P, s4.x);
    unsigned long long v1 = pack_p(P, s4.y);
    unsigned long long v2 = pack_p(P, s4.z);
    unsigned long long v3 = pack_p(P, s4.w);
    atomicAdd(&acc[d4.x], v0);
    atomicAdd(&acc[d4.y], v1);
    atomicAdd(&acc[d4.z], v2);
    atomicAdd(&acc[d4.w], v3);
}

// ---- final: unpack, divide by embedded degree, add bias ----
__global__ void out_final(const unsigned long long* __restrict__ acc_c,
                          const unsigned long long* __restrict__ acc_d,
                          const float* __restrict__ bout, float* __restrict__ out) {
    int v = blockIdx.x * blockDim.x + threadIdx.x;
    if (v >= NT) return;
    unsigned long long xc = acc_c[v];
    unsigned long long xd = acc_d[v];
    int dc = (int)(xc >> 52);
    int dd = (int)(xd >> 52);
    float ic = dc > 0 ? 1.0f / (float)dc : 0.0f;
    float id = dd > 0 ? 1.0f / (float)dd : 0.0f;
    float c0 = (float)((long long)((xc >> 26) & FIELD_MASK) - (long long)dc * PACK_BIAS);
    float c1 = (float)((long long)(xc & FIELD_MASK) - (long long)dc * PACK_BIAS);
    float d0 = (float)((long long)((xd >> 26) & FIELD_MASK) - (long long)dd * PACK_BIAS);
    float d1 = (float)((long long)(xd & FIELD_MASK) - (long long)dd * PACK_BIAS);
    const float inv_s = 1.0f / PACK_SCALE;
    float2 o;
    o.x = bout[0] + (c0 * ic + d0 * id) * inv_s;
    o.y = bout[1] + (c1 * ic + d1 * id) * inv_s;
    *(float2*)(out + 2 * (size_t)v) = o;
}

extern "C" void kernel_launch(void* const* d_in, const int* in_sizes, int n_in,
                              void* d_out, int out_size, void* d_ws, size_t ws_size,
                              hipStream_t stream) {
    const float* features = (const float*)d_in[0];
    const float* W1 = (const float*)d_in[3];
    const float* b1 = (const float*)d_in[4];
    const float* W2 = (const float*)d_in[5];
    const float* b2 = (const float*)d_in[6];
    const float* W_out = (const float*)d_in[7];
    const float* b_out = (const float*)d_in[8];
    const int* src_c2t = (const int*)d_in[9];
    const int* dst_c2t = (const int*)d_in[10];
    const int* src_t2c = (const int*)d_in[11];
    const int* dst_t2c = (const int*)d_in[12];
    const int* src_d2t = (const int*)d_in[13];
    const int* dst_d2t = (const int*)d_in[14];
    const int* src_t2d = (const int*)d_in[15];
    const int* dst_t2d = (const int*)d_in[16];
    float* out = (float*)d_out;

    // ---- workspace carve ----
    // zero region (contiguous): cnt_t2c, cnt_t2d, acc_c, acc_d
    int* wsi = (int*)d_ws;
    int* cnt_t2c = wsi;                                       // NC ints
    int* cnt_t2d = cnt_t2c + NC;                              // ND ints
    unsigned long long* acc_c = (unsigned long long*)(cnt_t2d + ND);  // NT u64
    unsigned long long* acc_d = acc_c + NT;                   // NT u64
    size_t zero_bytes = (size_t)(NC + ND) * 4 + (size_t)NT * 16;
    // non-zeroed region
    int* cols_t2c = (int*)(acc_d + NT);                       // NC*CAP_T2C
    int* cols_t2d = cols_t2c + (size_t)NC * CAP_T2C;          // ND*CAP_T2D
    float* p_c = (float*)(cols_t2d + (size_t)ND * CAP_T2D);   // NC*2
    float* p_d = p_c + (size_t)NC * 2;                        // ND*2
    float* Wc = p_d + (size_t)ND * 2;                         // 256
    float* bc = Wc + 256;                                     // 4

    hipMemsetAsync(d_ws, 0, zero_bytes, stream);

    const int B = 256;

    build_ell<<<(NE / 2 + B - 1) / B, B, 0, stream>>>(
        src_t2c, dst_t2c, src_t2d, dst_t2d,
        cnt_t2c, cols_t2c, cnt_t2d, cols_t2d);

    prep_fold<<<1, 256, 0, stream>>>(W2, b2, W_out, Wc, bc);

    gather_xform<<<NBLK_C + NBLK_D, 1024, 0, stream>>>(
        features, cnt_t2c, cols_t2c, cnt_t2d, cols_t2d,
        W1, b1, Wc, bc, p_c, p_d);

    scatter_pack<<<(NE / 2 + B - 1) / B, B, 0, stream>>>(
        p_c, p_d, src_c2t, dst_c2t, src_d2t, dst_d2t, acc_c, acc_d);

    out_final<<<(NT + B - 1) / B, B, 0, stream>>>(acc_c, acc_d, b_out, out);
}

// Round 7
// 486.867 us; speedup vs baseline: 1.1090x; 1.1090x over previous
//
#include <hip/hip_runtime.h>
#include <hip/hip_bf16.h>

// HeteroRGCN, minimal-random-line-op design + deep-prefetch gather:
//   p_c = lrelu(mask(mean_t2c(x) @ W1[1] + b1[1])) @ (W2[0]@W_out) + b2[0]@W_out
//   p_d = same with W1[3], W2[2]
//   out[t] = b_out + mean_c2t(p_c) + mean_d2t(p_d)
// Layer-1: ELL gather, wave-per-4-nodes with prefetched cnt/cols (32-deep MLP).
// Layer-2: ONE packed uint64 fixed-point atomicAdd per edge.

#define NT 500000
#define NC 200000
#define ND 100000
#define NE 1000000
#define H  64
#define CAP_T2C 32   // dst NC, lambda=5  (Poisson tail ~1e-15)
#define CAP_T2D 48   // dst ND, lambda=10 (Poisson tail ~1e-19)
#define BLK_NODES 32
#define NBLK_C (NC / BLK_NODES)   // 6250
#define NBLK_D (ND / BLK_NODES)   // 3125

#define PACK_SCALE 65536.0f
#define PACK_BIAS  262144   // 4 * 65536
#define FIELD_MASK 0x3FFFFFFULL

// ---- build ELL for t2c/t2d (ILP=4) ----
__global__ void build_ell(const int* __restrict__ st2c, const int* __restrict__ dt2c,
                          const int* __restrict__ st2d, const int* __restrict__ dt2d,
                          int* __restrict__ cnt_t2c, int* __restrict__ cols_t2c,
                          int* __restrict__ cnt_t2d, int* __restrict__ cols_t2d) {
    const int Q = NE / 4;  // 250000 threads per relation
    int i = blockIdx.x * blockDim.x + threadIdx.x;
    if (i >= 2 * Q) return;
    int sec = i / Q;
    int r = i - sec * Q;
    const int* sp = (sec == 0) ? st2c : st2d;
    const int* dp = (sec == 0) ? dt2c : dt2d;
    int* cnt = (sec == 0) ? cnt_t2c : cnt_t2d;
    int* cols = (sec == 0) ? cols_t2c : cols_t2d;
    int cap = (sec == 0) ? CAP_T2C : CAP_T2D;
    int4 s4 = ((const int4*)sp)[r];
    int4 d4 = ((const int4*)dp)[r];
    int p0 = atomicAdd(&cnt[d4.x], 1);
    int p1 = atomicAdd(&cnt[d4.y], 1);
    int p2 = atomicAdd(&cnt[d4.z], 1);
    int p3 = atomicAdd(&cnt[d4.w], 1);
    if (p0 < cap) cols[(size_t)d4.x * cap + p0] = s4.x;
    if (p1 < cap) cols[(size_t)d4.y * cap + p1] = s4.y;
    if (p2 < cap) cols[(size_t)d4.z * cap + p2] = s4.z;
    if (p3 < cap) cols[(size_t)d4.w * cap + p3] = s4.w;
}

// ---- fold W2[rel] @ W_out -> Wc (2 x 64 x 2), b2[rel] @ W_out -> bc (2 x 2) ----
__global__ void prep_fold(const float* __restrict__ W2, const float* __restrict__ b2,
                          const float* __restrict__ Wout,
                          float* __restrict__ Wc, float* __restrict__ bc) {
    int t = threadIdx.x;
    int rel = t >> 7;          // 0 -> W2[0], 1 -> W2[2]
    int rem = t & 127;
    int k = rem >> 1, o = rem & 1;
    const float* W2r = W2 + (rel ? 2 : 0) * H * H;
    float s = 0.0f;
    for (int j = 0; j < H; ++j) s += W2r[k * H + j] * Wout[j * 2 + o];
    Wc[rel * 128 + k * 2 + o] = s;
    if (rem < 4) {
        int r2 = rem >> 1, o2 = rem & 1;
        const float* b2r = b2 + (r2 ? 2 : 0) * H;
        float sb = 0.0f;
        for (int j = 0; j < H; ++j) sb += b2r[j] * Wout[j * 2 + o2];
        bc[r2 * 2 + o2] = sb;
    }
}

// up to 8 predicated independent row-gathers for one node
__device__ __forceinline__ float g8(const float* __restrict__ X, int cv, int m,
                                    int base, int lane) {
    int take = m - base;
    if (take <= 0) return 0.0f;
    float a0 = 0.f, a1 = 0.f, a2 = 0.f, a3 = 0.f, a4 = 0.f, a5 = 0.f, a6 = 0.f, a7 = 0.f;
    a0 = X[(size_t)__shfl(cv, base + 0) * H + lane];
    if (take > 1) a1 = X[(size_t)__shfl(cv, base + 1) * H + lane];
    if (take > 2) a2 = X[(size_t)__shfl(cv, base + 2) * H + lane];
    if (take > 3) a3 = X[(size_t)__shfl(cv, base + 3) * H + lane];
    if (take > 4) a4 = X[(size_t)__shfl(cv, base + 4) * H + lane];
    if (take > 5) a5 = X[(size_t)__shfl(cv, base + 5) * H + lane];
    if (take > 6) a6 = X[(size_t)__shfl(cv, base + 6) * H + lane];
    if (take > 7) a7 = X[(size_t)__shfl(cv, base + 7) * H + lane];
    return ((a0 + a1) + (a2 + a3)) + ((a4 + a5) + (a6 + a7));
}

// ---- fused gather-mean + transform + lrelu + mask + fold, both relations ----
// 512 threads = 8 waves; 32 nodes/block; wave-per-4-nodes with deep prefetch.
__global__ __launch_bounds__(512)
void gather_xform(const float* __restrict__ X,
                  const int* __restrict__ cnt_c, const int* __restrict__ cols_c,
                  const int* __restrict__ cnt_d, const int* __restrict__ cols_d,
                  const float* __restrict__ W1, const float* __restrict__ b1,
                  const float* __restrict__ Wc, const float* __restrict__ bc,
                  float* __restrict__ Pc, float* __restrict__ Pd) {
    __shared__ float Xs[BLK_NODES][65];   // [node][k], conflict-free both phases
    __shared__ float msk[BLK_NODES];
    int t = threadIdx.x;
    int lane = t & 63;
    int w = t >> 6;            // 8 waves

    int bn, cap;
    const int* cnt; const int* cols;
    const float* W1r; const float* b1r; const float* Wcr; const float* bcr;
    float* P;
    if (blockIdx.x < NBLK_C) {
        bn = blockIdx.x * BLK_NODES; cap = CAP_T2C;
        cnt = cnt_c; cols = cols_c;
        W1r = W1 + 1 * H * H; b1r = b1 + 1 * H; Wcr = Wc; bcr = bc; P = Pc;
    } else {
        bn = (blockIdx.x - NBLK_C) * BLK_NODES; cap = CAP_T2D;
        cnt = cnt_d; cols = cols_d;
        W1r = W1 + 3 * H * H; b1r = b1 + 3 * H; Wcr = Wc + 128; bcr = bc + 2; P = Pd;
    }

    // ---- phase A: wave handles 4 nodes; prefetch cnt + cols rows, then gather ----
    int gnb = bn + w * 4;
    int cval = (lane < 4) ? cnt[gnb + lane] : 0;     // one load for 4 counts
    int c0 = __shfl(cval, 0), c1 = __shfl(cval, 1);
    int c2 = __shfl(cval, 2), c3 = __shfl(cval, 3);
    int m0 = c0 < cap ? c0 : cap, m1 = c1 < cap ? c1 : cap;
    int m2 = c2 < cap ? c2 : cap, m3 = c3 < cap ? c3 : cap;
    // 4 independent cols-row loads
    int cv0 = (lane < m0) ? cols[(size_t)(gnb + 0) * cap + lane] : 0;
    int cv1 = (lane < m1) ? cols[(size_t)(gnb + 1) * cap + lane] : 0;
    int cv2 = (lane < m2) ? cols[(size_t)(gnb + 2) * cap + lane] : 0;
    int cv3 = (lane < m3) ? cols[(size_t)(gnb + 3) * cap + lane] : 0;

    float a0 = 0.f, a1 = 0.f, a2 = 0.f, a3 = 0.f;
    for (int base = 0; base < cap; base += 8) {
        if (base >= m0 && base >= m1 && base >= m2 && base >= m3) break;
        // 4 independent 8-deep gather bundles -> up to 32 loads in flight
        a0 += g8(X, cv0, m0, base, lane);
        a1 += g8(X, cv1, m1, base, lane);
        a2 += g8(X, cv2, m2, base, lane);
        a3 += g8(X, cv3, m3, base, lane);
    }
    Xs[w * 4 + 0][lane] = c0 > 0 ? a0 * (1.0f / (float)c0) : 0.0f;
    Xs[w * 4 + 1][lane] = c1 > 0 ? a1 * (1.0f / (float)c1) : 0.0f;
    Xs[w * 4 + 2][lane] = c2 > 0 ? a2 * (1.0f / (float)c2) : 0.0f;
    Xs[w * 4 + 3][lane] = c3 > 0 ? a3 * (1.0f / (float)c3) : 0.0f;
    if (lane < 4) msk[w * 4 + lane] = (cval > 0) ? 1.0f : 0.0f;
    __syncthreads();

    // ---- phase B: thread = (node t>>4, cols (t&15)*4 .. +3) ----
    int nl = t >> 4;           // 0..31
    int gn = bn + nl;
    int cc = (t & 15) * 4;
    float4 b4 = *(const float4*)(b1r + cc);
    float h0 = b4.x, h1 = b4.y, h2 = b4.z, h3 = b4.w;
#pragma unroll
    for (int k = 0; k < H; ++k) {
        float xv = Xs[nl][k];                              // LDS broadcast
        float4 wv = *(const float4*)(W1r + k * H + cc);    // global, L1-hot
        h0 = fmaf(xv, wv.x, h0); h1 = fmaf(xv, wv.y, h1);
        h2 = fmaf(xv, wv.z, h2); h3 = fmaf(xv, wv.w, h3);
    }
    float m = msk[nl];
    h0 = (h0 > 0.f ? h0 : 0.01f * h0) * m;
    h1 = (h1 > 0.f ? h1 : 0.01f * h1) * m;
    h2 = (h2 > 0.f ? h2 : 0.01f * h2) * m;
    h3 = (h3 > 0.f ? h3 : 0.01f * h3) * m;
    float4 wca = *(const float4*)(Wcr + cc * 2);       // cols cc,cc+1
    float4 wcb = *(const float4*)(Wcr + cc * 2 + 4);   // cols cc+2,cc+3
    float p0 = h0 * wca.x + h1 * wca.z + h2 * wcb.x + h3 * wcb.z;
    float p1 = h0 * wca.y + h1 * wca.w + h2 * wcb.y + h3 * wcb.w;
#pragma unroll
    for (int off = 1; off < 16; off <<= 1) {
        p0 += __shfl_xor(p0, off);
        p1 += __shfl_xor(p1, off);
    }
    if ((t & 15) == 0) {
        float2 o = make_float2(p0 + bcr[0], p1 + bcr[1]);
        *(float2*)(P + 2 * (size_t)gn) = o;
    }
}

// ---- pack p into fixed-point uint64 with embedded degree count ----
__device__ __forceinline__ unsigned long long pack_p(const float* __restrict__ P, int s) {
    float2 pv = *(const float2*)(P + 2 * (size_t)s);
    float a = fminf(fmaxf(pv.x, -3.99f), 3.99f);
    float b = fminf(fmaxf(pv.y, -3.99f), 3.99f);
    unsigned int ia = (unsigned int)(__float2int_rn(a * PACK_SCALE) + PACK_BIAS);
    unsigned int ib = (unsigned int)(__float2int_rn(b * PACK_SCALE) + PACK_BIAS);
    return (1ULL << 52) | ((unsigned long long)ia << 26) | (unsigned long long)ib;
}

// ---- layer-2: one uint64 atomic per edge (fire-and-forget), ILP=4 ----
__global__ void scatter_pack(const float* __restrict__ Pc, const float* __restrict__ Pd,
                             const int* __restrict__ sc2t, const int* __restrict__ dc2t,
                             const int* __restrict__ sd2t, const int* __restrict__ dd2t,
                             unsigned long long* __restrict__ acc_c,
                             unsigned long long* __restrict__ acc_d) {
    const int Q = NE / 4;
    int i = blockIdx.x * blockDim.x + threadIdx.x;
    if (i >= 2 * Q) return;
    int rel = i / Q;
    int r = i - rel * Q;
    const int* sp = rel ? sd2t : sc2t;
    const int* dp = rel ? dd2t : dc2t;
    const float* P = rel ? Pd : Pc;
    unsigned long long* acc = rel ? acc_d : acc_c;
    int4 s4 = ((const int4*)sp)[r];
    int4 d4 = ((const int4*)dp)[r];
    unsigned long long v0 = pack_p(P, s4.x);
    unsigned long long v1 = pack_p(P, s4.y);
    unsigned long long v2 = pack_p(P, s4.z);
    unsigned long long v3 = pack_p(P, s4.w);
    atomicAdd(&acc[d4.x], v0);
    atomicAdd(&acc[d4.y], v1);
    atomicAdd(&acc[d4.z], v2);
    atomicAdd(&acc[d4.w], v3);
}

// ---- final: unpack, divide by embedded degree, add bias ----
__global__ void out_final(const unsigned long long* __restrict__ acc_c,
                          const unsigned long long* __restrict__ acc_d,
                          const float* __restrict__ bout, float* __restrict__ out) {
    int v = blockIdx.x * blockDim.x + threadIdx.x;
    if (v >= NT) return;
    unsigned long long xc = acc_c[v];
    unsigned long long xd = acc_d[v];
    int dc = (int)(xc >> 52);
    int dd = (int)(xd >> 52);
    float ic = dc > 0 ? 1.0f / (float)dc : 0.0f;
    float id = dd > 0 ? 1.0f / (float)dd : 0.0f;
    float c0 = (float)((long long)((xc >> 26) & FIELD_MASK) - (long long)dc * PACK_BIAS);
    float c1 = (float)((long long)(xc & FIELD_MASK) - (long long)dc * PACK_BIAS);
    float d0 = (float)((long long)((xd >> 26) & FIELD_MASK) - (long long)dd * PACK_BIAS);
    float d1 = (float)((long long)(xd & FIELD_MASK) - (long long)dd * PACK_BIAS);
    const float inv_s = 1.0f / PACK_SCALE;
    float2 o;
    o.x = bout[0] + (c0 * ic + d0 * id) * inv_s;
    o.y = bout[1] + (c1 * ic + d1 * id) * inv_s;
    *(float2*)(out + 2 * (size_t)v) = o;
}

extern "C" void kernel_launch(void* const* d_in, const int* in_sizes, int n_in,
                              void* d_out, int out_size, void* d_ws, size_t ws_size,
                              hipStream_t stream) {
    const float* features = (const float*)d_in[0];
    const float* W1 = (const float*)d_in[3];
    const float* b1 = (const float*)d_in[4];
    const float* W2 = (const float*)d_in[5];
    const float* b2 = (const float*)d_in[6];
    const float* W_out = (const float*)d_in[7];
    const float* b_out = (const float*)d_in[8];
    const int* src_c2t = (const int*)d_in[9];
    const int* dst_c2t = (const int*)d_in[10];
    const int* src_t2c = (const int*)d_in[11];
    const int* dst_t2c = (const int*)d_in[12];
    const int* src_d2t = (const int*)d_in[13];
    const int* dst_d2t = (const int*)d_in[14];
    const int* src_t2d = (const int*)d_in[15];
    const int* dst_t2d = (const int*)d_in[16];
    float* out = (float*)d_out;

    // ---- workspace carve ----
    // zero region (contiguous): cnt_t2c, cnt_t2d, acc_c, acc_d
    int* wsi = (int*)d_ws;
    int* cnt_t2c = wsi;                                       // NC ints
    int* cnt_t2d = cnt_t2c + NC;                              // ND ints
    unsigned long long* acc_c = (unsigned long long*)(cnt_t2d + ND);  // NT u64
    unsigned long long* acc_d = acc_c + NT;                   // NT u64
    size_t zero_bytes = (size_t)(NC + ND) * 4 + (size_t)NT * 16;
    // non-zeroed region
    int* cols_t2c = (int*)(acc_d + NT);                       // NC*CAP_T2C
    int* cols_t2d = cols_t2c + (size_t)NC * CAP_T2C;          // ND*CAP_T2D
    float* p_c = (float*)(cols_t2d + (size_t)ND * CAP_T2D);   // NC*2
    float* p_d = p_c + (size_t)NC * 2;                        // ND*2
    float* Wc = p_d + (size_t)ND * 2;                         // 256
    float* bc = Wc + 256;                                     // 4

    hipMemsetAsync(d_ws, 0, zero_bytes, stream);

    const int B = 256;

    build_ell<<<(NE / 2 + B - 1) / B, B, 0, stream>>>(
        src_t2c, dst_t2c, src_t2d, dst_t2d,
        cnt_t2c, cols_t2c, cnt_t2d, cols_t2d);

    prep_fold<<<1, 256, 0, stream>>>(W2, b2, W_out, Wc, bc);

    gather_xform<<<NBLK_C + NBLK_D, 512, 0, stream>>>(
        features, cnt_t2c, cols_t2c, cnt_t2d, cols_t2d,
        W1, b1, Wc, bc, p_c, p_d);

    scatter_pack<<<(NE / 2 + B - 1) / B, B, 0, stream>>>(
        p_c, p_d, src_c2t, dst_c2t, src_d2t, dst_d2t, acc_c, acc_d);

    out_final<<<(NT + B - 1) / B, B, 0, stream>>>(acc_c, acc_d, b_out, out);
}